// Round 6
// baseline (1071.473 us; speedup 1.0000x reference)
//
#include <hip/hip_runtime.h>

// TreeTransformer on MI355X: bf16 MFMA pipeline.
// B=32,A=64 -> S=2048 sequences, N=121 tokens, H=128, heads=4(hd=32), NL=2, OUT=256.
// r5: r4 with the mlp writeback bug fixed (4 uint4 stores/lane, full 32-col
// quarter; r4 wrote only 16 of 32 cols -> half of X stale -> absmax 1.29).

typedef unsigned short u16;
typedef __attribute__((ext_vector_type(8))) short bf16x8;  // 8 bf16 (4 VGPRs)
typedef __attribute__((ext_vector_type(4))) float f32x4;

#define NTOK 121
#define HD 128
#define S_TOT 2048
#define EPSF 1e-5f

union U4 { uint4 u; u16 h[8]; };

__device__ inline u16 f2bf(float f) {  // round-to-nearest-even fp32->bf16
  unsigned u = __float_as_uint(f);
  return (u16)((u + 0x7FFFu + ((u >> 16) & 1u)) >> 16);
}
__device__ inline float bf2f(u16 h) { return __uint_as_float(((unsigned)h) << 16); }

__device__ inline f32x4 mfma16(bf16x8 a, bf16x8 b, f32x4 c) {
  return __builtin_amdgcn_mfma_f32_16x16x32_bf16(a, b, c, 0, 0, 0);
}

// ---------------- weight fp32 -> bf16 conversion -------------------------
__global__ __launch_bounds__(256) void convw_kernel(
    const float* __restrict__ qkvw, const float* __restrict__ projw,
    const float* __restrict__ ff1w, const float* __restrict__ ff2w,
    const float* __restrict__ wout, u16* __restrict__ dst) {
  int i = blockIdx.x * 256 + threadIdx.x;  // grid sized exactly 4161536/256
  float v;
  if (i < 98304) v = qkvw[i];
  else if (i < 131072) v = projw[i - 98304];
  else if (i < 163840) v = ff1w[i - 131072];
  else if (i < 196608) v = ff2w[i - 163840];
  else v = wout[i - 196608];
  dst[i] = f2bf(v);
}

// ---------------- input projection + tree PE + permutation ---------------
__global__ __launch_bounds__(256) void inproj_kernel(
    const float* __restrict__ forest, const int* __restrict__ adj,
    const int* __restrict__ perm, const float* __restrict__ WIN,
    const float* __restrict__ BIN, u16* __restrict__ X) {
  __shared__ float wf[128 * 12];
  __shared__ float fr[121 * 12];
  __shared__ float pe[121 * 12];
  __shared__ int pm[121];
  int s = blockIdx.x, tid = threadIdx.x;
  const float* fg = forest + (size_t)s * (NTOK * 12);
  const int* ag = adj + (size_t)s * (120 * 3);
  for (int i = tid; i < 128 * 12; i += 256) wf[i] = WIN[i];
  for (int i = tid; i < 121 * 12; i += 256) { fr[i] = fg[i]; pe[i] = 0.f; }
  if (tid < 121) pm[tid] = perm[tid];
  __syncthreads();
  if (tid > 0 && tid < 121) {
    int n = tid;
    int l = (n <= 3) ? 1 : (n <= 12) ? 2 : (n <= 39) ? 3 : 4;
    int cur = n;
    while (cur > 0) {
      int par = ag[(cur - 1) * 3];
      int br = ag[(cur - 1) * 3 + 2];
      pe[n * 12 + (l - 1) * 3 + br] = 1.f;
      cur = par; l--;
    }
  }
  __syncthreads();
  int h = tid & 127;
  for (int base = 0; base < 121; base += 2) {
    int i = base + (tid >> 7);
    if (i < 121) {
      int node = pm[i];
      float v = BIN[h];
#pragma unroll
      for (int k = 0; k < 12; ++k) v += fr[node * 12 + k] * wf[h * 12 + k];
      if (h < 12) v += pe[node * 12 + h];
      X[(size_t)s * (NTOK * HD) + i * HD + h] = f2bf(v);
    }
  }
}

// ---------------- barrier-free fused attention ---------------------------
// r1 topology: grid 4096, WG = (seq, head-pair hp). 4 waves; wave = (head
// slot hs = wave>>1, half = wave&1). Phase 1: wave builds K,V for its 64
// tokens of head (hp*2+hs), KEEPING the 16 X A-frags in registers; ONE
// barrier; phase 2: same rows as Q (register reuse) -> logits -> softmax ->
// P@V -> O. LDS 49152B: per head-slot K 8KB + Vt 8KB, per wave P 4KB. 3 WG/CU.
__global__ __launch_bounds__(256, 3) void attn_kernel(
    const u16* __restrict__ X, u16* __restrict__ O,
    const u16* __restrict__ WQKV, const float* __restrict__ QKVB, int layer) {
  __shared__ u16 lds[24576];
  int tid = threadIdx.x;
  int wave = tid >> 6, lane = tid & 63, l16 = lane & 15, quad = lane >> 4;
  int seq = blockIdx.x >> 1;
  int head = ((blockIdx.x & 1) << 1) | (wave >> 1);
  int half = wave & 1;
  int hs = wave >> 1;
  u16* Kh = lds + hs * 4096;          // K[t][d]: t*32 + ((d>>3 ^ t&3)<<3) + (d&7)
  u16* Vh = lds + 8192 + hs * 4096;   // Vt[d][t]: d*128 + ((t>>3 ^ d&15)<<3) + (t&7)
  u16* Pw = lds + 16384 + wave * 2048;  // P[q][t] (q-tile overlaid at base)
  const u16* Xs = X + (size_t)seq * (NTOK * HD);
  const f32x4 fz = {0.f, 0.f, 0.f, 0.f};
  const int wbase = layer * 384 + head * 32;
  const u16* WQ = WQKV + (size_t)wbase * HD;
  const u16* WK = WQKV + (size_t)(wbase + 128) * HD;
  const u16* WV = WQKV + (size_t)(wbase + 256) * HD;

  // ---- phase 1: K, V^T for tokens [half*64, half*64+64) of this head ----
  bf16x8 xa[4][4];  // X A-fragments for rows half*64..+63; kept for phase 2
#pragma unroll
  for (int mt = 0; mt < 4; ++mt) {
    int tb = half * 64 + mt * 16;
    int arow = tb + l16; if (arow > 120) arow = 120;  // pad rows: any valid data
#pragma unroll
    for (int k = 0; k < 4; ++k)
      xa[mt][k] = *(const bf16x8*)(Xs + (size_t)arow * HD + k * 32 + quad * 8);
#pragma unroll
    for (int nt = 0; nt < 2; ++nt) {
      f32x4 kacc = fz, vacc = fz;
#pragma unroll
      for (int k = 0; k < 4; ++k) {
        bf16x8 bk = *(const bf16x8*)(WK + (size_t)(nt * 16 + l16) * HD + k * 32 + quad * 8);
        bf16x8 bv = *(const bf16x8*)(WV + (size_t)(nt * 16 + l16) * HD + k * 32 + quad * 8);
        kacc = mfma16(xa[mt][k], bk, kacc);
        vacc = mfma16(xa[mt][k], bv, vacc);
      }
      float kb = QKVB[wbase + 128 + nt * 16 + l16];
      float vb = QKVB[wbase + 256 + nt * 16 + l16];
      int d = nt * 16 + l16;
      int kc = nt * 2 + (l16 >> 3);  // d>>3
#pragma unroll
      for (int r = 0; r < 4; ++r) {
        int t = tb + quad * 4 + r;
        Kh[t * 32 + ((kc ^ (t & 3)) << 3) + (l16 & 7)] = f2bf(kacc[r] + kb);
        float vv = (t < NTOK) ? (vacc[r] + vb) : 0.f;  // zero pad rows
        Vh[d * 128 + (((t >> 3) ^ l16) << 3) + (t & 7)] = f2bf(vv);
      }
    }
  }
  __syncthreads();  // the ONLY barrier

  // ---- phase 2: 4 query M-tiles per wave (same rows; X frags reused) ----
  const float scl = 0.17677669529663687f * 1.4426950408889634f;  // 1/sqrt(32)*log2(e)
  for (int qi = 0; qi < 4; ++qi) {
    int qb = (half * 4 + qi) * 16;
#pragma unroll
    for (int nt = 0; nt < 2; ++nt) {
      f32x4 qacc = fz;
#pragma unroll
      for (int k = 0; k < 4; ++k)
        qacc = mfma16(xa[qi][k], *(const bf16x8*)(WQ + (size_t)(nt * 16 + l16) * HD + k * 32 + quad * 8), qacc);
      float qbias = QKVB[wbase + nt * 16 + l16];
      int kc = nt * 2 + (l16 >> 3);
#pragma unroll
      for (int r = 0; r < 4; ++r) {
        int m = quad * 4 + r;
        Pw[m * 32 + ((kc ^ (m & 3)) << 3) + (l16 & 7)] = f2bf((qacc[r] + qbias) * scl);
      }
    }
    // logits (K-dim = 32 = single mfma k-step)
    bf16x8 qa = *(const bf16x8*)(Pw + l16 * 32 + ((quad ^ (l16 & 3)) << 3));
    f32x4 lg[8];
#pragma unroll
    for (int nt = 0; nt < 8; ++nt)
      lg[nt] = mfma16(qa, *(const bf16x8*)(Kh + (nt * 16 + l16) * 32 + ((quad ^ (l16 & 3)) << 3)), fz);
    if (l16 >= 9) lg[7] = (f32x4){-3e38f, -3e38f, -3e38f, -3e38f};  // mask cols 121..127
    float rinv[4];
#pragma unroll
    for (int r = 0; r < 4; ++r) {
      float mx = lg[0][r];
#pragma unroll
      for (int nt = 1; nt < 8; ++nt) mx = fmaxf(mx, lg[nt][r]);
      mx = fmaxf(mx, __shfl_xor(mx, 1)); mx = fmaxf(mx, __shfl_xor(mx, 2));
      mx = fmaxf(mx, __shfl_xor(mx, 4)); mx = fmaxf(mx, __shfl_xor(mx, 8));
      float e[8], sum = 0.f;
#pragma unroll
      for (int nt = 0; nt < 8; ++nt) {
        e[nt] = __builtin_amdgcn_exp2f(lg[nt][r] - mx);
        sum += e[nt];
      }
      sum += __shfl_xor(sum, 1); sum += __shfl_xor(sum, 2);
      sum += __shfl_xor(sum, 4); sum += __shfl_xor(sum, 8);
      rinv[r] = __builtin_amdgcn_rcpf(sum);  // normalize deferred to O epilogue
      int qr = quad * 4 + r;
#pragma unroll
      for (int nt = 0; nt < 8; ++nt)
        Pw[qr * 128 + (((nt * 2 + (l16 >> 3)) ^ qr) << 3) + (l16 & 7)] = f2bf(e[nt]);
    }
    // P @ V (K-dim = 128 tokens = 4 k-steps)
#pragma unroll
    for (int pnt = 0; pnt < 2; ++pnt) {
      f32x4 oacc = fz;
#pragma unroll
      for (int ks = 0; ks < 4; ++ks) {
        bf16x8 pa = *(const bf16x8*)(Pw + l16 * 128 + (((ks * 4 + quad) ^ l16) << 3));
        bf16x8 vb = *(const bf16x8*)(Vh + (pnt * 16 + l16) * 128 + (((ks * 4 + quad) ^ l16) << 3));
        oacc = mfma16(pa, vb, oacc);
      }
#pragma unroll
      for (int r = 0; r < 4; ++r) {
        int row = qb + quad * 4 + r;
        if (row < NTOK)
          O[(size_t)seq * (NTOK * HD) + (size_t)row * HD + head * 32 + pnt * 16 + l16] =
              f2bf(oacc[r] * rinv[r]);
      }
    }
  }
}

// ------- barrier-free fused proj+res+LN1+ff1+relu+ff2+res+LN2 ------------
// 64 rows/WG, grid 3872 (rows are seq-contiguous; all ops row-local so tiles
// may span sequence boundaries). Each wave owns 16 rows end-to-end: proj
// (8 N-tiles x 4 k = 32 MFMA), LN1 in C-layout registers (l16 shuffles),
// wave-private LDS transpose -> ff1 -> relu -> ff2 -> LN2 -> coalesced store.
// ZERO __syncthreads. LDS 17472B.
__global__ __launch_bounds__(256, 3) void mlp_kernel(
    u16* __restrict__ X, const u16* __restrict__ O,
    const u16* __restrict__ WP, const float* __restrict__ PB,
    const u16* __restrict__ W1, const float* __restrict__ B1,
    const u16* __restrict__ W2, const float* __restrict__ B2,
    const float* __restrict__ G1, const float* __restrict__ Bt1,
    const float* __restrict__ G2, const float* __restrict__ Bt2, int layer) {
  __shared__ u16 tile[4][2184];  // per-wave 16x136 (+pad)
  int tid = threadIdx.x;
  int wave = tid >> 6, lane = tid & 63, l16 = lane & 15, quad = lane >> 4;
  int R0 = blockIdx.x * 64 + wave * 16;  // this wave's 16 rows
  u16* T = tile[wave];
  const f32x4 fz = {0.f, 0.f, 0.f, 0.f};
  const int lb = layer * 128;

  // O A-fragments (rows R0..R0+15 straight from global)
  bf16x8 oa[4];
#pragma unroll
  for (int k = 0; k < 4; ++k)
    oa[k] = *(const bf16x8*)(O + (size_t)(R0 + l16) * HD + k * 32 + quad * 8);

  // proj GEMM: 8 N-tiles x 4 k-steps
  f32x4 acc[8];
#pragma unroll
  for (int nt = 0; nt < 8; ++nt) acc[nt] = fz;
#pragma unroll
  for (int k = 0; k < 4; ++k)
#pragma unroll
    for (int nt = 0; nt < 8; ++nt)
      acc[nt] = mfma16(oa[k],
          *(const bf16x8*)(WP + (size_t)(lb + nt * 16 + l16) * HD + k * 32 + quad * 8),
          acc[nt]);

  // LN1 in C-layout registers: lane holds rows quad*4+r, cols nt*16+l16
  float sum[4] = {0.f, 0.f, 0.f, 0.f}, ssq[4] = {0.f, 0.f, 0.f, 0.f};
  float vv[8][4];
#pragma unroll
  for (int nt = 0; nt < 8; ++nt) {
    int c = nt * 16 + l16;
    float pb = PB[lb + c];
#pragma unroll
    for (int r = 0; r < 4; ++r) {
      float res = bf2f(X[(size_t)(R0 + quad * 4 + r) * HD + c]);
      float t = acc[nt][r] + pb + res;
      vv[nt][r] = t; sum[r] += t; ssq[r] += t * t;
    }
  }
#pragma unroll
  for (int m = 1; m <= 8; m <<= 1)
#pragma unroll
    for (int r = 0; r < 4; ++r) { sum[r] += __shfl_xor(sum[r], m); ssq[r] += __shfl_xor(ssq[r], m); }
  float mean[4], rstd[4];
#pragma unroll
  for (int r = 0; r < 4; ++r) {
    mean[r] = sum[r] * (1.f / 128.f);
    rstd[r] = rsqrtf(ssq[r] * (1.f / 128.f) - mean[r] * mean[r] + EPSF);
  }
  unsigned x1p[8][2];  // x1 (post-LN1) bf16-packed, kept as LN2 residual
#pragma unroll
  for (int nt = 0; nt < 8; ++nt) {
    int c = nt * 16 + l16;
    float g = G1[lb + c], bt = Bt1[lb + c];
    u16 h[4];
#pragma unroll
    for (int r = 0; r < 4; ++r) {
      h[r] = f2bf((vv[nt][r] - mean[r]) * rstd[r] * g + bt);
      T[(quad * 4 + r) * 136 + c] = h[r];  // transpose to A-layout via LDS
    }
    x1p[nt][0] = (unsigned)h[0] | ((unsigned)h[1] << 16);
    x1p[nt][1] = (unsigned)h[2] | ((unsigned)h[3] << 16);
  }
  bf16x8 xf[4];
#pragma unroll
  for (int k = 0; k < 4; ++k)
    xf[k] = *(const bf16x8*)(T + l16 * 136 + k * 32 + quad * 8);

  // ff1 + relu
  f32x4 a2[8];
#pragma unroll
  for (int nt = 0; nt < 8; ++nt) a2[nt] = fz;
#pragma unroll
  for (int k = 0; k < 4; ++k)
#pragma unroll
    for (int nt = 0; nt < 8; ++nt)
      a2[nt] = mfma16(xf[k],
          *(const bf16x8*)(W1 + (size_t)(lb + nt * 16 + l16) * HD + k * 32 + quad * 8),
          a2[nt]);
#pragma unroll
  for (int nt = 0; nt < 8; ++nt) {
    int c = nt * 16 + l16;
    float b1 = B1[lb + c];
#pragma unroll
    for (int r = 0; r < 4; ++r)
      T[(quad * 4 + r) * 136 + c] = f2bf(fmaxf(a2[nt][r] + b1, 0.f));
  }
  bf16x8 hf[4];
#pragma unroll
  for (int k = 0; k < 4; ++k)
    hf[k] = *(const bf16x8*)(T + l16 * 136 + k * 32 + quad * 8);

  // ff2
  f32x4 a3[8];
#pragma unroll
  for (int nt = 0; nt < 8; ++nt) a3[nt] = fz;
#pragma unroll
  for (int k = 0; k < 4; ++k)
#pragma unroll
    for (int nt = 0; nt < 8; ++nt)
      a3[nt] = mfma16(hf[k],
          *(const bf16x8*)(W2 + (size_t)(lb + nt * 16 + l16) * HD + k * 32 + quad * 8),
          a3[nt]);

  // LN2 (residual = x1 from registers)
#pragma unroll
  for (int r = 0; r < 4; ++r) { sum[r] = 0.f; ssq[r] = 0.f; }
#pragma unroll
  for (int nt = 0; nt < 8; ++nt) {
    int c = nt * 16 + l16;
    float b2 = B2[lb + c];
#pragma unroll
    for (int r = 0; r < 4; ++r) {
      float x1v = bf2f((u16)(x1p[nt][r >> 1] >> ((r & 1) * 16)));
      float t = a3[nt][r] + b2 + x1v;
      vv[nt][r] = t; sum[r] += t; ssq[r] += t * t;
    }
  }
#pragma unroll
  for (int m = 1; m <= 8; m <<= 1)
#pragma unroll
    for (int r = 0; r < 4; ++r) { sum[r] += __shfl_xor(sum[r], m); ssq[r] += __shfl_xor(ssq[r], m); }
#pragma unroll
  for (int r = 0; r < 4; ++r) {
    mean[r] = sum[r] * (1.f / 128.f);
    rstd[r] = rsqrtf(ssq[r] * (1.f / 128.f) - mean[r] * mean[r] + EPSF);
  }
#pragma unroll
  for (int nt = 0; nt < 8; ++nt) {
    int c = nt * 16 + l16;
    float g = G2[lb + c], bt = Bt2[lb + c];
#pragma unroll
    for (int r = 0; r < 4; ++r)
      T[(quad * 4 + r) * 136 + c] = f2bf((vv[nt][r] - mean[r]) * rstd[r] * g + bt);
  }
  // coalesced writeback: lane -> (row = lane>>2, 32-col quarter = (lane&3)*32)
  // 4 x uint4 (8 u16 each) covers the full 32-col quarter.  [r5 fix]
  int orow = lane >> 2, oc = (lane & 3) * 32;
#pragma unroll
  for (int i = 0; i < 4; ++i) {
    uint4 w = *(const uint4*)(T + orow * 136 + oc + i * 8);
    *(uint4*)(X + (size_t)(R0 + orow) * HD + oc + i * 8) = w;
  }
}

// ---------------- final GEMM (M=2048,K=15488,N=256), split-K=16 ----------
// 32-row M-tiles: grid (64,16) = 1024 WGs -> 4 WG/CU.
__global__ __launch_bounds__(256, 4) void outgemm_kernel(
    const u16* __restrict__ X, const u16* __restrict__ WO, float* __restrict__ PART) {
  __shared__ u16 as_[32 * 136];
  int mtile = blockIdx.x, j = blockIdx.y;
  int tid = threadIdx.x, wave = tid >> 6, lane = tid & 63, l16 = lane & 15, quad = lane >> 4;
  int s0 = mtile * 32;
  int k0 = (j * 484) / 16, k1 = ((j + 1) * 484) / 16;  // k-steps of 32 over K=15488
  const f32x4 fz = {0.f, 0.f, 0.f, 0.f};
  f32x4 acc[2][4];
  for (int a = 0; a < 2; ++a) for (int b = 0; b < 4; ++b) acc[a][b] = fz;
  for (int kb = k0; kb < k1; kb += 4) {
    int nst = (k1 - kb < 4) ? (k1 - kb) : 4;
    __syncthreads();
    int chunks = 32 * 4 * nst;
    for (int c = tid; c < chunks; c += 256) {
      int rr = c / (4 * nst), g = c % (4 * nst);
      *(uint4*)(as_ + rr * 136 + g * 8) =
          *(const uint4*)(X + (size_t)(s0 + rr) * 15488 + kb * 32 + g * 8);
    }
    __syncthreads();
    for (int kk = 0; kk < nst; ++kk) {
      bf16x8 af[2];
#pragma unroll
      for (int mt = 0; mt < 2; ++mt)
        af[mt] = *(const bf16x8*)(as_ + (mt * 16 + l16) * 136 + kk * 32 + quad * 8);
#pragma unroll
      for (int n = 0; n < 4; ++n) {
        int nt = wave * 4 + n;
        bf16x8 bf = *(const bf16x8*)(WO + (size_t)(nt * 16 + l16) * 15488 +
                                     (size_t)(kb + kk) * 32 + quad * 8);
#pragma unroll
        for (int mt = 0; mt < 2; ++mt) acc[mt][n] = mfma16(af[mt], bf, acc[mt][n]);
      }
    }
  }
  for (int mt = 0; mt < 2; ++mt)
    for (int n = 0; n < 4; ++n) {
      int nt = wave * 4 + n;
#pragma unroll
      for (int r = 0; r < 4; ++r) {
        int row = s0 + mt * 16 + quad * 4 + r;
        PART[((size_t)j * 2048 + row) * 256 + nt * 16 + l16] = acc[mt][n][r];
      }
    }
}

// ---------------- reduce split-K partials + bias + final LN --------------
__global__ __launch_bounds__(256) void lnf_kernel(
    const float* __restrict__ PART, const float* __restrict__ BO,
    const float* __restrict__ G, const float* __restrict__ Bt, float* __restrict__ OUT) {
  int s = blockIdx.x * 4 + (threadIdx.x >> 6);  // one wave per sequence
  int lane = threadIdx.x & 63;
  float v[4], sum = 0.f, ssq = 0.f;
#pragma unroll
  for (int i = 0; i < 4; ++i) {
    int c = lane + i * 64;
    float t = BO[c];
    for (int jj = 0; jj < 16; ++jj) t += PART[((size_t)jj * 2048 + s) * 256 + c];
    v[i] = t; sum += t; ssq += t * t;
  }
  for (int m = 1; m <= 32; m <<= 1) { sum += __shfl_xor(sum, m, 64); ssq += __shfl_xor(ssq, m, 64); }
  float mean = sum * (1.f / 256.f);
  float var = ssq * (1.f / 256.f) - mean * mean;
  float rstd = rsqrtf(var + EPSF);
#pragma unroll
  for (int i = 0; i < 4; ++i) {
    int c = lane + i * 64;
    OUT[(size_t)s * 256 + c] = (v[i] - mean) * rstd * G[c] + Bt[c];
  }
}

extern "C" void kernel_launch(void* const* d_in, const int* in_sizes, int n_in,
                              void* d_out, int out_size, void* d_ws, size_t ws_size,
                              hipStream_t stream) {
  const float* forest = (const float*)d_in[0];
  const int* adj      = (const int*)d_in[1];
  const int* perm     = (const int*)d_in[2];
  const float* w_in   = (const float*)d_in[3];
  const float* b_in   = (const float*)d_in[4];
  const float* qkv_w  = (const float*)d_in[5];
  const float* qkv_b  = (const float*)d_in[6];
  const float* proj_w = (const float*)d_in[7];
  const float* proj_b = (const float*)d_in[8];
  const float* ff1_w  = (const float*)d_in[9];
  const float* ff1_b  = (const float*)d_in[10];
  const float* ff2_w  = (const float*)d_in[11];
  const float* ff2_b  = (const float*)d_in[12];
  const float* ln1_g  = (const float*)d_in[13];
  const float* ln1_b  = (const float*)d_in[14];
  const float* ln2_g  = (const float*)d_in[15];
  const float* ln2_b  = (const float*)d_in[16];
  const float* w_out  = (const float*)d_in[17];
  const float* b_out  = (const float*)d_in[18];
  const float* lnf_g  = (const float*)d_in[19];
  const float* lnf_b  = (const float*)d_in[20];

  // workspace map (bytes): bf16 weights 8,323,072 | X 63,438,848 | O 63,438,848 | PART 33,554,432
  char* ws = (char*)d_ws;
  u16* WB = (u16*)ws;
  u16* X  = (u16*)(ws + 8323072);
  u16* O  = (u16*)(ws + 8323072 + 63438848);
  float* PART = (float*)(ws + 8323072 + 2 * (size_t)63438848);

  u16* WQKV  = WB;
  u16* WPROJ = WB + 98304;
  u16* WFF1  = WB + 131072;
  u16* WFF2  = WB + 163840;
  u16* WOUT  = WB + 196608;

  convw_kernel<<<16256, 256, 0, stream>>>(qkv_w, proj_w, ff1_w, ff2_w, w_out, WB);
  inproj_kernel<<<2048, 256, 0, stream>>>(forest, adj, perm, w_in, b_in, X);
  for (int layer = 0; layer < 2; ++layer) {
    attn_kernel<<<4096, 256, 0, stream>>>(X, O, WQKV, qkv_b, layer);
    mlp_kernel<<<3872, 256, 0, stream>>>(X, O, WPROJ, proj_b, WFF1, ff1_b, WFF2, ff2_b,
                                         ln1_g, ln1_b, ln2_g, ln2_b, layer);
  }
  outgemm_kernel<<<dim3(64, 16), 256, 0, stream>>>(X, WOUT, PART);
  lnf_kernel<<<512, 256, 0, stream>>>(PART, b_out, lnf_g, lnf_b, (float*)d_out);
}

// Round 7
// 898.136 us; speedup vs baseline: 1.1930x; 1.1930x over previous
//
#include <hip/hip_runtime.h>

// TreeTransformer on MI355X: bf16 MFMA pipeline.
// B=32,A=64 -> S=2048 sequences, N=121 tokens, H=128, heads=4(hd=32), NL=2, OUT=256.
// r6: revert to best-measured components (r1 attn topology/phase1, r2 fused mlp,
// 32-row outgemm). RULE learned r5: never hold register arrays across a barrier
// (allocator targets ~84 VGPR and spills to scratch: +268MB fetch/write).
// Experiment: attn phase-2 processes q-tiles in PAIRS (dual-q ILP, zero LDS
// growth, short live ranges): Q-gemm x2 -> logits x2 -> softmax0->P0->PV0
// overlapped with softmax1(regs) -> P1->PV1.

typedef unsigned short u16;
typedef __attribute__((ext_vector_type(8))) short bf16x8;  // 8 bf16 (4 VGPRs)
typedef __attribute__((ext_vector_type(4))) float f32x4;

#define NTOK 121
#define HD 128
#define S_TOT 2048
#define EPSF 1e-5f

union U4 { uint4 u; u16 h[8]; };

__device__ inline u16 f2bf(float f) {  // round-to-nearest-even fp32->bf16
  unsigned u = __float_as_uint(f);
  return (u16)((u + 0x7FFFu + ((u >> 16) & 1u)) >> 16);
}
__device__ inline float bf2f(u16 h) { return __uint_as_float(((unsigned)h) << 16); }

__device__ inline f32x4 mfma16(bf16x8 a, bf16x8 b, f32x4 c) {
  return __builtin_amdgcn_mfma_f32_16x16x32_bf16(a, b, c, 0, 0, 0);
}

// ---------------- weight fp32 -> bf16 conversion -------------------------
__global__ __launch_bounds__(256) void convw_kernel(
    const float* __restrict__ qkvw, const float* __restrict__ projw,
    const float* __restrict__ ff1w, const float* __restrict__ ff2w,
    const float* __restrict__ wout, u16* __restrict__ dst) {
  int i = blockIdx.x * 256 + threadIdx.x;  // grid sized exactly 4161536/256
  float v;
  if (i < 98304) v = qkvw[i];
  else if (i < 131072) v = projw[i - 98304];
  else if (i < 163840) v = ff1w[i - 131072];
  else if (i < 196608) v = ff2w[i - 163840];
  else v = wout[i - 196608];
  dst[i] = f2bf(v);
}

// ---------------- input projection + tree PE + permutation ---------------
__global__ __launch_bounds__(256) void inproj_kernel(
    const float* __restrict__ forest, const int* __restrict__ adj,
    const int* __restrict__ perm, const float* __restrict__ WIN,
    const float* __restrict__ BIN, u16* __restrict__ X) {
  __shared__ float wf[128 * 12];
  __shared__ float fr[121 * 12];
  __shared__ float pe[121 * 12];
  __shared__ int pm[121];
  int s = blockIdx.x, tid = threadIdx.x;
  const float* fg = forest + (size_t)s * (NTOK * 12);
  const int* ag = adj + (size_t)s * (120 * 3);
  for (int i = tid; i < 128 * 12; i += 256) wf[i] = WIN[i];
  for (int i = tid; i < 121 * 12; i += 256) { fr[i] = fg[i]; pe[i] = 0.f; }
  if (tid < 121) pm[tid] = perm[tid];
  __syncthreads();
  if (tid > 0 && tid < 121) {
    int n = tid;
    int l = (n <= 3) ? 1 : (n <= 12) ? 2 : (n <= 39) ? 3 : 4;
    int cur = n;
    while (cur > 0) {
      int par = ag[(cur - 1) * 3];
      int br = ag[(cur - 1) * 3 + 2];
      pe[n * 12 + (l - 1) * 3 + br] = 1.f;
      cur = par; l--;
    }
  }
  __syncthreads();
  int h = tid & 127;
  for (int base = 0; base < 121; base += 2) {
    int i = base + (tid >> 7);
    if (i < 121) {
      int node = pm[i];
      float v = BIN[h];
#pragma unroll
      for (int k = 0; k < 12; ++k) v += fr[node * 12 + k] * wf[h * 12 + k];
      if (h < 12) v += pe[node * 12 + h];
      X[(size_t)s * (NTOK * HD) + i * HD + h] = f2bf(v);
    }
  }
}

// ---------------- barrier-free fused attention ---------------------------
// r1 topology: grid 4096, WG = (seq, head-pair hp). 4 waves; wave = (head
// slot hs = wave>>1, half = wave&1). Phase 1: wave builds K,V for its 64
// tokens (A-frags loaded fresh per tile, NOT held across the barrier); ONE
// barrier; phase 2: q-tiles processed in PAIRS for 2-way ILP.
// LDS 49152B: per head-slot K 8KB + Vt 8KB, per wave P 4KB. 3 WG/CU.
__global__ __launch_bounds__(256, 3) void attn_kernel(
    const u16* __restrict__ X, u16* __restrict__ O,
    const u16* __restrict__ WQKV, const float* __restrict__ QKVB, int layer) {
  __shared__ u16 lds[24576];
  int tid = threadIdx.x;
  int wave = tid >> 6, lane = tid & 63, l16 = lane & 15, quad = lane >> 4;
  int seq = blockIdx.x >> 1;
  int head = ((blockIdx.x & 1) << 1) | (wave >> 1);
  int half = wave & 1;
  int hs = wave >> 1;
  u16* Kh = lds + hs * 4096;          // K[t][d]: t*32 + ((d>>3 ^ t&3)<<3) + (d&7)
  u16* Vh = lds + 8192 + hs * 4096;   // Vt[d][t]: d*128 + ((t>>3 ^ d&15)<<3) + (t&7)
  u16* Pw = lds + 16384 + wave * 2048;  // P region; q0 at +0, q1 at +512 staged
  const u16* Xs = X + (size_t)seq * (NTOK * HD);
  const f32x4 fz = {0.f, 0.f, 0.f, 0.f};
  const int wbase = layer * 384 + head * 32;
  const u16* WQ = WQKV + (size_t)wbase * HD;
  const u16* WK = WQKV + (size_t)(wbase + 128) * HD;
  const u16* WV = WQKV + (size_t)(wbase + 256) * HD;

  // ---- phase 1: K, V^T for tokens [half*64, half*64+64) of this head ----
  for (int mt = 0; mt < 4; ++mt) {
    int tb = half * 64 + mt * 16;
    int arow = tb + l16; if (arow > 120) arow = 120;  // pad rows: any valid data
    bf16x8 a[4];
#pragma unroll
    for (int k = 0; k < 4; ++k)
      a[k] = *(const bf16x8*)(Xs + (size_t)arow * HD + k * 32 + quad * 8);
#pragma unroll
    for (int nt = 0; nt < 2; ++nt) {
      f32x4 kacc = fz, vacc = fz;
#pragma unroll
      for (int k = 0; k < 4; ++k) {
        bf16x8 bk = *(const bf16x8*)(WK + (size_t)(nt * 16 + l16) * HD + k * 32 + quad * 8);
        bf16x8 bv = *(const bf16x8*)(WV + (size_t)(nt * 16 + l16) * HD + k * 32 + quad * 8);
        kacc = mfma16(a[k], bk, kacc);
        vacc = mfma16(a[k], bv, vacc);
      }
      float kb = QKVB[wbase + 128 + nt * 16 + l16];
      float vb = QKVB[wbase + 256 + nt * 16 + l16];
      int d = nt * 16 + l16;
      int kc = nt * 2 + (l16 >> 3);  // d>>3
#pragma unroll
      for (int r = 0; r < 4; ++r) {
        int t = tb + quad * 4 + r;
        Kh[t * 32 + ((kc ^ (t & 3)) << 3) + (l16 & 7)] = f2bf(kacc[r] + kb);
        float vv = (t < NTOK) ? (vacc[r] + vb) : 0.f;  // zero pad rows
        Vh[d * 128 + (((t >> 3) ^ l16) << 3) + (t & 7)] = f2bf(vv);
      }
    }
  }
  __syncthreads();  // the ONLY barrier

  // ---- phase 2: q-tiles in pairs (dual-q ILP) ----
  const float scl = 0.17677669529663687f * 1.4426950408889634f;  // 1/sqrt(32)*log2(e)
  for (int qp = 0; qp < 2; ++qp) {
    int qb0 = (half * 4 + qp * 2) * 16;
    int qb1 = qb0 + 16;
    // A-frags for both tiles (fresh loads; L2-hot; die after Q-gemm)
    bf16x8 a0[4], a1[4];
    {
      int r0 = qb0 + l16; if (r0 > 120) r0 = 120;
      int r1_ = qb1 + l16; if (r1_ > 120) r1_ = 120;
#pragma unroll
      for (int k = 0; k < 4; ++k) {
        a0[k] = *(const bf16x8*)(Xs + (size_t)r0 * HD + k * 32 + quad * 8);
        a1[k] = *(const bf16x8*)(Xs + (size_t)r1_ * HD + k * 32 + quad * 8);
      }
    }
    // Q GEMM both tiles -> staging (q0 at Pw+0, q1 at Pw+512)
#pragma unroll
    for (int nt = 0; nt < 2; ++nt) {
      f32x4 qacc0 = fz, qacc1 = fz;
#pragma unroll
      for (int k = 0; k < 4; ++k) {
        bf16x8 wq = *(const bf16x8*)(WQ + (size_t)(nt * 16 + l16) * HD + k * 32 + quad * 8);
        qacc0 = mfma16(a0[k], wq, qacc0);
        qacc1 = mfma16(a1[k], wq, qacc1);
      }
      float qbias = QKVB[wbase + nt * 16 + l16];
      int kc = nt * 2 + (l16 >> 3);
#pragma unroll
      for (int r = 0; r < 4; ++r) {
        int m = quad * 4 + r;
        int idx = m * 32 + ((kc ^ (m & 3)) << 3) + (l16 & 7);
        Pw[idx]       = f2bf((qacc0[r] + qbias) * scl);
        Pw[512 + idx] = f2bf((qacc1[r] + qbias) * scl);
      }
    }
    // logits for both tiles (16 independent MFMAs; K-frag shared)
    bf16x8 qa0 = *(const bf16x8*)(Pw + l16 * 32 + ((quad ^ (l16 & 3)) << 3));
    bf16x8 qa1 = *(const bf16x8*)(Pw + 512 + l16 * 32 + ((quad ^ (l16 & 3)) << 3));
    f32x4 lg0[8], lg1[8];
#pragma unroll
    for (int nt = 0; nt < 8; ++nt) {
      bf16x8 kf = *(const bf16x8*)(Kh + (nt * 16 + l16) * 32 + ((quad ^ (l16 & 3)) << 3));
      lg0[nt] = mfma16(qa0, kf, fz);
      lg1[nt] = mfma16(qa1, kf, fz);
    }
    if (l16 >= 9) {  // mask cols 121..127
      lg0[7] = (f32x4){-3e38f, -3e38f, -3e38f, -3e38f};
      lg1[7] = (f32x4){-3e38f, -3e38f, -3e38f, -3e38f};
    }
    // softmax tile0 -> P0 straight into LDS (overwrites q staging; qa read done)
    float rinv0[4];
#pragma unroll
    for (int r = 0; r < 4; ++r) {
      float mx = lg0[0][r];
#pragma unroll
      for (int nt = 1; nt < 8; ++nt) mx = fmaxf(mx, lg0[nt][r]);
      mx = fmaxf(mx, __shfl_xor(mx, 1)); mx = fmaxf(mx, __shfl_xor(mx, 2));
      mx = fmaxf(mx, __shfl_xor(mx, 4)); mx = fmaxf(mx, __shfl_xor(mx, 8));
      float e[8], sum = 0.f;
#pragma unroll
      for (int nt = 0; nt < 8; ++nt) {
        e[nt] = __builtin_amdgcn_exp2f(lg0[nt][r] - mx);
        sum += e[nt];
      }
      sum += __shfl_xor(sum, 1); sum += __shfl_xor(sum, 2);
      sum += __shfl_xor(sum, 4); sum += __shfl_xor(sum, 8);
      rinv0[r] = __builtin_amdgcn_rcpf(sum);
      int qr = quad * 4 + r;
#pragma unroll
      for (int nt = 0; nt < 8; ++nt)
        Pw[qr * 128 + (((nt * 2 + (l16 >> 3)) ^ qr) << 3) + (l16 & 7)] = f2bf(e[nt]);
    }
    // softmax tile1 -> e1 kept in registers (VALU; co-schedules with PV0 MFMAs)
    float rinv1[4], e1[4][8];
#pragma unroll
    for (int r = 0; r < 4; ++r) {
      float mx = lg1[0][r];
#pragma unroll
      for (int nt = 1; nt < 8; ++nt) mx = fmaxf(mx, lg1[nt][r]);
      mx = fmaxf(mx, __shfl_xor(mx, 1)); mx = fmaxf(mx, __shfl_xor(mx, 2));
      mx = fmaxf(mx, __shfl_xor(mx, 4)); mx = fmaxf(mx, __shfl_xor(mx, 8));
      float sum = 0.f;
#pragma unroll
      for (int nt = 0; nt < 8; ++nt) {
        e1[r][nt] = __builtin_amdgcn_exp2f(lg1[nt][r] - mx);
        sum += e1[r][nt];
      }
      sum += __shfl_xor(sum, 1); sum += __shfl_xor(sum, 2);
      sum += __shfl_xor(sum, 4); sum += __shfl_xor(sum, 8);
      rinv1[r] = __builtin_amdgcn_rcpf(sum);
    }
    // PV tile0 (reads P0 region; in-order DS guarantees vs later P1 writes)
#pragma unroll
    for (int pnt = 0; pnt < 2; ++pnt) {
      f32x4 oacc = fz;
#pragma unroll
      for (int ks = 0; ks < 4; ++ks) {
        bf16x8 pa = *(const bf16x8*)(Pw + l16 * 128 + (((ks * 4 + quad) ^ l16) << 3));
        bf16x8 vb = *(const bf16x8*)(Vh + (pnt * 16 + l16) * 128 + (((ks * 4 + quad) ^ l16) << 3));
        oacc = mfma16(pa, vb, oacc);
      }
#pragma unroll
      for (int r = 0; r < 4; ++r) {
        int row = qb0 + quad * 4 + r;
        if (row < NTOK)
          O[(size_t)seq * (NTOK * HD) + (size_t)row * HD + head * 32 + pnt * 16 + l16] =
              f2bf(oacc[r] * rinv0[r]);
      }
    }
    // P1 write (after PV0 reads in program order), then PV tile1
#pragma unroll
    for (int r = 0; r < 4; ++r) {
      int qr = quad * 4 + r;
#pragma unroll
      for (int nt = 0; nt < 8; ++nt)
        Pw[qr * 128 + (((nt * 2 + (l16 >> 3)) ^ qr) << 3) + (l16 & 7)] = f2bf(e1[r][nt]);
    }
#pragma unroll
    for (int pnt = 0; pnt < 2; ++pnt) {
      f32x4 oacc = fz;
#pragma unroll
      for (int ks = 0; ks < 4; ++ks) {
        bf16x8 pa = *(const bf16x8*)(Pw + l16 * 128 + (((ks * 4 + quad) ^ l16) << 3));
        bf16x8 vb = *(const bf16x8*)(Vh + (pnt * 16 + l16) * 128 + (((ks * 4 + quad) ^ l16) << 3));
        oacc = mfma16(pa, vb, oacc);
      }
#pragma unroll
      for (int r = 0; r < 4; ++r) {
        int row = qb1 + quad * 4 + r;
        if (row < NTOK)
          O[(size_t)seq * (NTOK * HD) + (size_t)row * HD + head * 32 + pnt * 16 + l16] =
              f2bf(oacc[r] * rinv1[r]);
      }
    }
  }
}

// ------- fused proj+res+LN1+ff1+relu+ff2+res+LN2 (in-place on X) ---------
// One WG per 32 rows. LDS 34304B -> 4 WG/CU. as_ holds O then x1(post-LN1);
// hs holds relu(ff1); ct holds fp32 GEMM output tiles. (r2 version, measured)
__global__ __launch_bounds__(256, 4) void mlp_kernel(
    u16* __restrict__ X, const u16* __restrict__ O,
    const u16* __restrict__ WP, const float* __restrict__ PB,
    const u16* __restrict__ W1, const float* __restrict__ B1,
    const u16* __restrict__ W2, const float* __restrict__ B2,
    const float* __restrict__ G1, const float* __restrict__ Bt1,
    const float* __restrict__ G2, const float* __restrict__ Bt2, int layer) {
  __shared__ u16 as_[32 * 136];
  __shared__ u16 hs[32 * 136];
  __shared__ float ct[32 * 132];
  int r0 = blockIdx.x * 32, tid = threadIdx.x;
  int wave = tid >> 6, lane = tid & 63, l16 = lane & 15, quad = lane >> 4;
  const f32x4 fz = {0.f, 0.f, 0.f, 0.f};
  int row = tid >> 3, l8 = tid & 7;
  size_t R = (size_t)(r0 + row);

  // stage O
  for (int c = tid; c < 32 * 16; c += 256) {
    int rr = c >> 4, g = c & 15;
    *(uint4*)(as_ + rr * 136 + g * 8) = *(const uint4*)(O + (size_t)(r0 + rr) * HD + g * 8);
  }
  __syncthreads();
  // proj GEMM: as_ (O) x WP -> ct
  {
    f32x4 acc[2][2] = {{fz, fz}, {fz, fz}};
#pragma unroll
    for (int k = 0; k < 4; ++k) {
      bf16x8 a0 = *(const bf16x8*)(as_ + l16 * 136 + k * 32 + quad * 8);
      bf16x8 a1 = *(const bf16x8*)(as_ + (16 + l16) * 136 + k * 32 + quad * 8);
#pragma unroll
      for (int n = 0; n < 2; ++n) {
        int nt = wave * 2 + n;
        bf16x8 bf = *(const bf16x8*)(WP + ((size_t)(layer * 128 + nt * 16 + l16)) * HD + k * 32 + quad * 8);
        acc[0][n] = mfma16(a0, bf, acc[0][n]);
        acc[1][n] = mfma16(a1, bf, acc[1][n]);
      }
    }
    for (int mt = 0; mt < 2; ++mt)
      for (int n = 0; n < 2; ++n) {
        int nt = wave * 2 + n;
#pragma unroll
        for (int r = 0; r < 4; ++r)
          ct[(mt * 16 + quad * 4 + r) * 132 + nt * 16 + l16] = acc[mt][n][r];
      }
  }
  __syncthreads();
  // LN1: ct + PB + X(residual, global) -> x1 -> as_ (bf16)
  {
    U4 xa, xb;
    xa.u = *(const uint4*)(X + R * HD + l8 * 16);
    xb.u = *(const uint4*)(X + R * HD + l8 * 16 + 8);
    float v[16], sum = 0.f, ssq = 0.f;
#pragma unroll
    for (int i = 0; i < 16; ++i) {
      int c = l8 * 16 + i;
      float res = bf2f(i < 8 ? xa.h[i] : xb.h[i - 8]);
      float t = ct[row * 132 + c] + PB[layer * 128 + c] + res;
      v[i] = t; sum += t; ssq += t * t;
    }
    for (int m = 1; m <= 4; m <<= 1) { sum += __shfl_xor(sum, m, 64); ssq += __shfl_xor(ssq, m, 64); }
    float mean = sum * (1.f / 128.f);
    float var = ssq * (1.f / 128.f) - mean * mean;
    float rstd = rsqrtf(var + EPSF);
#pragma unroll
    for (int j = 0; j < 8; ++j) {
      int c = l8 * 16 + 2 * j;
      unsigned lo = f2bf((v[2 * j] - mean) * rstd * G1[layer * 128 + c] + Bt1[layer * 128 + c]);
      unsigned hi = f2bf((v[2 * j + 1] - mean) * rstd * G1[layer * 128 + c + 1] + Bt1[layer * 128 + c + 1]);
      *(unsigned*)(as_ + row * 136 + c) = lo | (hi << 16);
    }
  }
  __syncthreads();
  // ff1: as_ (x1) x W1 -> relu -> hs
  {
    f32x4 acc[2][2] = {{fz, fz}, {fz, fz}};
#pragma unroll
    for (int k = 0; k < 4; ++k) {
      bf16x8 a0 = *(const bf16x8*)(as_ + l16 * 136 + k * 32 + quad * 8);
      bf16x8 a1 = *(const bf16x8*)(as_ + (16 + l16) * 136 + k * 32 + quad * 8);
#pragma unroll
      for (int n = 0; n < 2; ++n) {
        int nt = wave * 2 + n;
        bf16x8 bf = *(const bf16x8*)(W1 + ((size_t)(layer * 128 + nt * 16 + l16)) * HD + k * 32 + quad * 8);
        acc[0][n] = mfma16(a0, bf, acc[0][n]);
        acc[1][n] = mfma16(a1, bf, acc[1][n]);
      }
    }
    for (int mt = 0; mt < 2; ++mt)
      for (int n = 0; n < 2; ++n) {
        int nt = wave * 2 + n;
        int col = nt * 16 + l16;
        float b1 = B1[layer * 128 + col];
#pragma unroll
        for (int r = 0; r < 4; ++r)
          hs[(mt * 16 + quad * 4 + r) * 136 + col] = f2bf(fmaxf(acc[mt][n][r] + b1, 0.f));
      }
  }
  __syncthreads();
  // ff2: hs x W2 -> ct
  {
    f32x4 acc[2][2] = {{fz, fz}, {fz, fz}};
#pragma unroll
    for (int k = 0; k < 4; ++k) {
      bf16x8 a0 = *(const bf16x8*)(hs + l16 * 136 + k * 32 + quad * 8);
      bf16x8 a1 = *(const bf16x8*)(hs + (16 + l16) * 136 + k * 32 + quad * 8);
#pragma unroll
      for (int n = 0; n < 2; ++n) {
        int nt = wave * 2 + n;
        bf16x8 bf = *(const bf16x8*)(W2 + ((size_t)(layer * 128 + nt * 16 + l16)) * HD + k * 32 + quad * 8);
        acc[0][n] = mfma16(a0, bf, acc[0][n]);
        acc[1][n] = mfma16(a1, bf, acc[1][n]);
      }
    }
    for (int mt = 0; mt < 2; ++mt)
      for (int n = 0; n < 2; ++n) {
        int nt = wave * 2 + n;
#pragma unroll
        for (int r = 0; r < 4; ++r)
          ct[(mt * 16 + quad * 4 + r) * 132 + nt * 16 + l16] = acc[mt][n][r];
      }
  }
  __syncthreads();
  // LN2: ct + B2 + as_ (x1 residual) -> X
  {
    float v[16], sum = 0.f, ssq = 0.f;
#pragma unroll
    for (int i = 0; i < 16; ++i) {
      int c = l8 * 16 + i;
      float t = ct[row * 132 + c] + B2[layer * 128 + c] + bf2f(as_[row * 136 + c]);
      v[i] = t; sum += t; ssq += t * t;
    }
    for (int m = 1; m <= 4; m <<= 1) { sum += __shfl_xor(sum, m, 64); ssq += __shfl_xor(ssq, m, 64); }
    float mean = sum * (1.f / 128.f);
    float var = ssq * (1.f / 128.f) - mean * mean;
    float rstd = rsqrtf(var + EPSF);
    U4 o0, o1;
#pragma unroll
    for (int i = 0; i < 16; ++i) {
      int c = l8 * 16 + i;
      u16 b = f2bf((v[i] - mean) * rstd * G2[layer * 128 + c] + Bt2[layer * 128 + c]);
      if (i < 8) o0.h[i] = b; else o1.h[i - 8] = b;
    }
    *(uint4*)(X + R * HD + l8 * 16) = o0.u;
    *(uint4*)(X + R * HD + l8 * 16 + 8) = o1.u;
  }
}

// ---------------- final GEMM (M=2048,K=15488,N=256), split-K=16 ----------
// 32-row M-tiles: grid (64,16) = 1024 WGs -> 4 WG/CU.
__global__ __launch_bounds__(256, 4) void outgemm_kernel(
    const u16* __restrict__ X, const u16* __restrict__ WO, float* __restrict__ PART) {
  __shared__ u16 as_[32 * 136];
  int mtile = blockIdx.x, j = blockIdx.y;
  int tid = threadIdx.x, wave = tid >> 6, lane = tid & 63, l16 = lane & 15, quad = lane >> 4;
  int s0 = mtile * 32;
  int k0 = (j * 484) / 16, k1 = ((j + 1) * 484) / 16;  // k-steps of 32 over K=15488
  const f32x4 fz = {0.f, 0.f, 0.f, 0.f};
  f32x4 acc[2][4];
  for (int a = 0; a < 2; ++a) for (int b = 0; b < 4; ++b) acc[a][b] = fz;
  for (int kb = k0; kb < k1; kb += 4) {
    int nst = (k1 - kb < 4) ? (k1 - kb) : 4;
    __syncthreads();
    int chunks = 32 * 4 * nst;
    for (int c = tid; c < chunks; c += 256) {
      int rr = c / (4 * nst), g = c % (4 * nst);
      *(uint4*)(as_ + rr * 136 + g * 8) =
          *(const uint4*)(X + (size_t)(s0 + rr) * 15488 + kb * 32 + g * 8);
    }
    __syncthreads();
    for (int kk = 0; kk < nst; ++kk) {
      bf16x8 af[2];
#pragma unroll
      for (int mt = 0; mt < 2; ++mt)
        af[mt] = *(const bf16x8*)(as_ + (mt * 16 + l16) * 136 + kk * 32 + quad * 8);
#pragma unroll
      for (int n = 0; n < 4; ++n) {
        int nt = wave * 4 + n;
        bf16x8 bf = *(const bf16x8*)(WO + (size_t)(nt * 16 + l16) * 15488 +
                                     (size_t)(kb + kk) * 32 + quad * 8);
#pragma unroll
        for (int mt = 0; mt < 2; ++mt) acc[mt][n] = mfma16(af[mt], bf, acc[mt][n]);
      }
    }
  }
  for (int mt = 0; mt < 2; ++mt)
    for (int n = 0; n < 4; ++n) {
      int nt = wave * 4 + n;
#pragma unroll
      for (int r = 0; r < 4; ++r) {
        int row = s0 + mt * 16 + quad * 4 + r;
        PART[((size_t)j * 2048 + row) * 256 + nt * 16 + l16] = acc[mt][n][r];
      }
    }
}

// ---------------- reduce split-K partials + bias + final LN --------------
__global__ __launch_bounds__(256) void lnf_kernel(
    const float* __restrict__ PART, const float* __restrict__ BO,
    const float* __restrict__ G, const float* __restrict__ Bt, float* __restrict__ OUT) {
  int s = blockIdx.x * 4 + (threadIdx.x >> 6);  // one wave per sequence
  int lane = threadIdx.x & 63;
  float v[4], sum = 0.f, ssq = 0.f;
#pragma unroll
  for (int i = 0; i < 4; ++i) {
    int c = lane + i * 64;
    float t = BO[c];
    for (int jj = 0; jj < 16; ++jj) t += PART[((size_t)jj * 2048 + s) * 256 + c];
    v[i] = t; sum += t; ssq += t * t;
  }
  for (int m = 1; m <= 32; m <<= 1) { sum += __shfl_xor(sum, m, 64); ssq += __shfl_xor(ssq, m, 64); }
  float mean = sum * (1.f / 256.f);
  float var = ssq * (1.f / 256.f) - mean * mean;
  float rstd = rsqrtf(var + EPSF);
#pragma unroll
  for (int i = 0; i < 4; ++i) {
    int c = lane + i * 64;
    OUT[(size_t)s * 256 + c] = (v[i] - mean) * rstd * G[c] + Bt[c];
  }
}

extern "C" void kernel_launch(void* const* d_in, const int* in_sizes, int n_in,
                              void* d_out, int out_size, void* d_ws, size_t ws_size,
                              hipStream_t stream) {
  const float* forest = (const float*)d_in[0];
  const int* adj      = (const int*)d_in[1];
  const int* perm     = (const int*)d_in[2];
  const float* w_in   = (const float*)d_in[3];
  const float* b_in   = (const float*)d_in[4];
  const float* qkv_w  = (const float*)d_in[5];
  const float* qkv_b  = (const float*)d_in[6];
  const float* proj_w = (const float*)d_in[7];
  const float* proj_b = (const float*)d_in[8];
  const float* ff1_w  = (const float*)d_in[9];
  const float* ff1_b  = (const float*)d_in[10];
  const float* ff2_w  = (const float*)d_in[11];
  const float* ff2_b  = (const float*)d_in[12];
  const float* ln1_g  = (const float*)d_in[13];
  const float* ln1_b  = (const float*)d_in[14];
  const float* ln2_g  = (const float*)d_in[15];
  const float* ln2_b  = (const float*)d_in[16];
  const float* w_out  = (const float*)d_in[17];
  const float* b_out  = (const float*)d_in[18];
  const float* lnf_g  = (const float*)d_in[19];
  const float* lnf_b  = (const float*)d_in[20];

  // workspace map (bytes): bf16 weights 8,323,072 | X 63,438,848 | O 63,438,848 | PART 33,554,432
  char* ws = (char*)d_ws;
  u16* WB = (u16*)ws;
  u16* X  = (u16*)(ws + 8323072);
  u16* O  = (u16*)(ws + 8323072 + 63438848);
  float* PART = (float*)(ws + 8323072 + 2 * (size_t)63438848);

  u16* WQKV  = WB;
  u16* WPROJ = WB + 98304;
  u16* WFF1  = WB + 131072;
  u16* WFF2  = WB + 163840;
  u16* WOUT  = WB + 196608;

  convw_kernel<<<16256, 256, 0, stream>>>(qkv_w, proj_w, ff1_w, ff2_w, w_out, WB);
  inproj_kernel<<<2048, 256, 0, stream>>>(forest, adj, perm, w_in, b_in, X);
  for (int layer = 0; layer < 2; ++layer) {
    attn_kernel<<<4096, 256, 0, stream>>>(X, O, WQKV, qkv_b, layer);
    mlp_kernel<<<7744, 256, 0, stream>>>(X, O, WPROJ, proj_b, WFF1, ff1_b, WFF2, ff2_b,
                                         ln1_g, ln1_b, ln2_g, ln2_b, layer);
  }
  outgemm_kernel<<<dim3(64, 16), 256, 0, stream>>>(X, WOUT, PART);
  lnf_kernel<<<512, 256, 0, stream>>>(PART, b_out, lnf_g, lnf_b, (float*)d_out);
}